// Round 24
// baseline (172.140 us; speedup 1.0000x reference)
//
#include <hip/hip_runtime.h>
#include <math.h>
#include <stdint.h>

#define BB 4
#define TT 2048
#define CC 1024
#define HH 16
#define DH 64
#define BT (BB*TT)      // 8192
#define NQKV (3*HH*DH)  // 3072

typedef __attribute__((ext_vector_type(8))) __bf16 bf16x8;
typedef __attribute__((ext_vector_type(4))) float f32x4;
typedef __attribute__((ext_vector_type(16))) float f32x16;
typedef __attribute__((ext_vector_type(8))) unsigned short u16x8;
typedef __attribute__((ext_vector_type(4))) unsigned short u16x4;
typedef __attribute__((ext_vector_type(4))) unsigned int u32x4;

__device__ __forceinline__ unsigned short f2b(float f) {
  union { float f; unsigned u; } v; v.f = f;
  unsigned r = v.u + 0x7fffu + ((v.u >> 16) & 1u);
  return (unsigned short)(r >> 16);
}

__device__ __forceinline__ void gload_lds16(const void* g, void* lds) {
  __builtin_amdgcn_global_load_lds(
      (const __attribute__((address_space(1))) void*)(uintptr_t)g,
      (__attribute__((address_space(3))) void*)(uintptr_t)lds, 16, 0, 0);
}

__device__ __forceinline__ unsigned cvtpk_bf16(float lo, float hi) {
  unsigned r;
  asm("v_cvt_pk_bf16_f32 %0, %1, %2" : "=v"(r) : "v"(lo), "v"(hi));
  return r;
}

__device__ __forceinline__ float fexp2(float x) {
#if __has_builtin(__builtin_amdgcn_exp2f)
  return __builtin_amdgcn_exp2f(x);
#else
  float r; asm("v_exp_f32 %0, %1" : "=v"(r) : "v"(x)); return r;
#endif
}

// ---------- merged prep: x->bf16, QKV weight transpose, Wproj transpose ----------
__global__ __launch_bounds__(256) void prep_all(
    const float* __restrict__ x,
    const float* __restrict__ Wq, const float* __restrict__ Wk, const float* __restrict__ Wv,
    const float* __restrict__ Wproj,
    unsigned short* __restrict__ xb, unsigned short* __restrict__ Wt,
    unsigned short* __restrict__ WpT)
{
  __shared__ float tile[32][33];
  const int bid = blockIdx.x;
  const int tid = threadIdx.x;

  if (bid < 4096) {                       // ---- cvt_bf16: x -> xb
    int i = (bid * 256 + tid) * 8;
    float4 a = *(const float4*)(x + i);
    float4 b = *(const float4*)(x + i + 4);
    u16x8 pk;
    pk[0] = f2b(a.x); pk[1] = f2b(a.y); pk[2] = f2b(a.z); pk[3] = f2b(a.w);
    pk[4] = f2b(b.x); pk[5] = f2b(b.y); pk[6] = f2b(b.z); pk[7] = f2b(b.w);
    *(u16x8*)(xb + i) = pk;
    return;
  }

  const int tx = tid & 31, ty = tid >> 5;  // flattened 32x8
  if (bid < 7168) {                        // ---- QKV transpose: [16][C][DH]x3 -> [48][DH][C]
    const int id = bid - 4096;             // = z*64 + ry*2 + rx
    const int rx = id & 1, ry = (id >> 1) & 31, z = id >> 6;
    const float* in = (z < 16 ? Wq : (z < 32 ? Wk : Wv)) + (size_t)(z & 15) * CC * DH;
    unsigned short* o = Wt + (size_t)z * CC * DH;
    const int r0 = ry * 32, c0 = rx * 32;
    #pragma unroll
    for (int i = 0; i < 32; i += 8)
      tile[ty + i][tx] = in[(size_t)(r0 + ty + i) * DH + c0 + tx];
    __syncthreads();
    #pragma unroll
    for (int i = 0; i < 32; i += 8)
      o[(size_t)(c0 + ty + i) * CC + r0 + tx] = f2b(tile[tx][ty + i]);
    return;
  }

  {                                        // ---- Wproj transpose: [C][C] -> [C][C]^T
    const int id = bid - 7168;             // = ry*32 + rx
    const int rx = id & 31, ry = id >> 5;
    const int r0 = ry * 32, c0 = rx * 32;
    #pragma unroll
    for (int i = 0; i < 32; i += 8)
      tile[ty + i][tx] = Wproj[(size_t)(r0 + ty + i) * CC + c0 + tx];
    __syncthreads();
    #pragma unroll
    for (int i = 0; i < 32; i += 8)
      WpT[(size_t)(c0 + ty + i) * CC + r0 + tx] = f2b(tile[tx][ty + i]);
  }
}

// ---------- bf16 MFMA GEMM (BK=64, XOR-swizzled LDS, single-barrier dbuf) ----------
// r22 version (best verified). r23 lesson: counted-vmcnt graft on this
// 2-barrier structure is NULL (matches guide m131) — implicit wave overlap
// at 2 blocks/CU already covers the drain. r20 lesson: 64KB LDS / 2 blocks/CU
// is the L2-dictated optimum (8x8 co-resident tile rectangle = 4MB = L2).
template<int MODE>
__global__ __launch_bounds__(256) void mfma_gemm(
    const unsigned short* __restrict__ A,
    const unsigned short* __restrict__ Bt,
    void* __restrict__ Cout, unsigned short* __restrict__ VTout,
    int M, int N, int K)
{
  __shared__ unsigned short As[2 * 128 * 64];   // 32 KB (2 buffers)
  __shared__ unsigned short Bs[2 * 128 * 64];   // 32 KB
  const int tid = threadIdx.x;
  const int l = tid & 63, w = tid >> 6;
  const int wr = w >> 1, wc = w & 1;

  const int wid = blockIdx.y * gridDim.x + blockIdx.x;
  const int local = wid >> 3;
  const int rt = (wid & 7) * 8 + (local & 7);
  const int ct = local >> 3;
  const long row0 = (long)rt * 128, col0 = (long)ct * 128;

  const bool SWAP = (MODE == 1) || (ct < 16);   // block-uniform

  const int srowA = w * 32 + (l >> 3);
  const int schunk = (l & 7) ^ ((l >> 3) & 7);
  const unsigned short* Ap = A + (row0 + srowA) * (long)K + schunk * 8;
  const unsigned short* Bp = Bt + (col0 + srowA) * (long)K + schunk * 8;
  const size_t woff = (size_t)w * 4096;

  f32x4 acc[4][4];
  #pragma unroll
  for (int i = 0; i < 4; ++i)
    #pragma unroll
    for (int j = 0; j < 4; ++j) acc[i][j] = (f32x4){0.f, 0.f, 0.f, 0.f};

  const int fr = l & 15, fg = l >> 4;
  const int fswz = fr & 7;

  // prologue: stage K-tile 0 into buffer 0
  #pragma unroll
  for (int i = 0; i < 4; ++i) {
    gload_lds16(Ap + (size_t)i * 8 * K, (char*)As + woff + i * 1024);
    gload_lds16(Bp + (size_t)i * 8 * K, (char*)Bs + woff + i * 1024);
  }
  __syncthreads();

  const int NT = K >> 6;
  for (int kt = 0; kt < NT; ++kt) {
    const int cur = kt & 1;
    if (kt + 1 < NT) {                       // prefetch next tile into buf^1
      const long k0 = (long)(kt + 1) * 64;
      char* Ad = (char*)As + (cur ^ 1) * 16384 + woff;
      char* Bd = (char*)Bs + (cur ^ 1) * 16384 + woff;
      #pragma unroll
      for (int i = 0; i < 4; ++i) {
        gload_lds16(Ap + (size_t)i * 8 * K + k0, Ad + i * 1024);
        gload_lds16(Bp + (size_t)i * 8 * K + k0, Bd + i * 1024);
      }
    }
    const char* aB = (const char*)As + cur * 16384;
    const char* bB = (const char*)Bs + cur * 16384;
    #pragma unroll
    for (int kk = 0; kk < 2; ++kk) {
      bf16x8 af[4], bfr[4];
      #pragma unroll
      for (int m = 0; m < 4; ++m)
        af[m] = *(const bf16x8*)(aB + (wr * 64 + m * 16 + fr) * 128 + (((fg + kk * 4) ^ fswz) << 4));
      #pragma unroll
      for (int n = 0; n < 4; ++n)
        bfr[n] = *(const bf16x8*)(bB + (wc * 64 + n * 16 + fr) * 128 + (((fg + kk * 4) ^ fswz) << 4));
      if (SWAP) {
        #pragma unroll
        for (int m = 0; m < 4; ++m)
          #pragma unroll
          for (int n = 0; n < 4; ++n)
            acc[m][n] = __builtin_amdgcn_mfma_f32_16x16x32_bf16(bfr[n], af[m], acc[m][n], 0, 0, 0);
      } else {
        #pragma unroll
        for (int m = 0; m < 4; ++m)
          #pragma unroll
          for (int n = 0; n < 4; ++n)
            acc[m][n] = __builtin_amdgcn_mfma_f32_16x16x32_bf16(af[m], bfr[n], acc[m][n], 0, 0, 0);
      }
    }
    __syncthreads();   // publish prefetched buf^1; protect reuse of buf cur
  }

  const int fq = l >> 4;
  if (MODE == 1) {
    #pragma unroll
    for (int m = 0; m < 4; ++m) {
      long grow = row0 + wr * 64 + m * 16 + fr;
      #pragma unroll
      for (int n = 0; n < 4; ++n) {
        long gcol0 = col0 + wc * 64 + n * 16 + fq * 4;
        float4 v = make_float4(acc[m][n][0], acc[m][n][1], acc[m][n][2], acc[m][n][3]);
        *(float4*)&((float*)Cout)[grow * (long)N + gcol0] = v;
      }
    }
  } else if (ct < 16) {
    // Q/K, SWAP layout: reg r -> d (4 contiguous). u16x4 stores.
    #pragma unroll
    for (int m = 0; m < 4; ++m) {
      int t = (int)(row0 + wr * 64 + m * 16 + fr);
      int b = t >> 11, tt = t & 2047;
      #pragma unroll
      for (int n = 0; n < 4; ++n) {
        long gcol0 = col0 + wc * 64 + n * 16 + fq * 4;
        int which = (int)(gcol0 >> 10);
        int h = (int)((gcol0 >> 6) & 15);
        int d0 = (int)(gcol0 & 63);
        float sc = (which == 0) ? 0.04508422017f : 1.f;  // C^-0.5 * log2(e) into Q
        u16x4 pk;
        #pragma unroll
        for (int r = 0; r < 4; ++r) pk[r] = f2b(acc[m][n][r] * sc);
        *(u16x4*)&((unsigned short*)Cout)[((((size_t)which * BB + b) * HH + h) * TT + tt) * DH + d0] = pk;
      }
    }
  } else {
    // V, normal layout: reg r -> t (4 contiguous). u16x4 into VT [bh][d][t].
    #pragma unroll
    for (int m = 0; m < 4; ++m) {
      long grow0 = row0 + wr * 64 + m * 16 + fq * 4;
      int b = (int)(grow0 >> 11), t0 = (int)(grow0 & 2047);
      #pragma unroll
      for (int n = 0; n < 4; ++n) {
        long gcol = col0 + wc * 64 + n * 16 + fr;
        int h = (int)((gcol >> 6) & 15);
        int d = (int)(gcol & 63);
        u16x4 pk;
        #pragma unroll
        for (int r = 0; r < 4; ++r) pk[r] = f2b(acc[m][n][r]);
        *(u16x4*)&VTout[((size_t)(b * HH + h) * DH + d) * TT + t0] = pk;
      }
    }
  }
}

// ---------- MFMA flash attention: unpaired q-tiles, QK-pair ILP reorder ----------
__device__ __forceinline__ int crow(int r, int hi) { return (r & 3) + 8 * (r >> 2) + 4 * hi; }

__device__ __forceinline__ void swap32(unsigned a, unsigned b, int hi,
                                       unsigned& L, unsigned& H) {
#if __has_builtin(__builtin_amdgcn_permlane32_swap)
  typedef unsigned uint2v __attribute__((ext_vector_type(2)));
  uint2v rr = __builtin_amdgcn_permlane32_swap(a, b, false, false);
  L = rr[0]; H = rr[1];
#else
  unsigned ax = __shfl_xor((int)a, 32, 64), bx = __shfl_xor((int)b, 32, 64);
  L = hi ? bx : a;
  H = hi ? b : ax;
#endif
}

// no-max softmax: P = exp2(S) (log2e pre-folded into Q), lane-local l accumulation.
__device__ __forceinline__ void sm_nomax(const f32x16& s, bool diag, int lq, int hi,
                                         float& lsum, bf16x8& pf0, bf16x8& pf1) {
  float p[16];
  #pragma unroll
  for (int r = 0; r < 16; ++r) {
    float e = fexp2(s[r]);
    if (diag && (crow(r, hi) > lq)) e = 0.f;
    p[r] = e;
  }
  float t[8];
  #pragma unroll
  for (int r = 0; r < 8; ++r) t[r] = p[r] + p[r + 8];
  #pragma unroll
  for (int r = 0; r < 4; ++r) t[r] = t[r] + t[r + 4];
  lsum += ((t[0] + t[1]) + (t[2] + t[3]));

  unsigned U[4][2];
  #pragma unroll
  for (int g = 0; g < 4; ++g) {
    U[g][0] = cvtpk_bf16(p[4 * g + 0], p[4 * g + 1]);
    U[g][1] = cvtpk_bf16(p[4 * g + 2], p[4 * g + 3]);
  }
  unsigned L0, H0, L1, H1;
  swap32(U[0][0], U[1][0], hi, L0, H0);
  swap32(U[0][1], U[1][1], hi, L1, H1);
  pf0 = __builtin_bit_cast(bf16x8, (u32x4){L0, L1, H0, H1});
  swap32(U[2][0], U[3][0], hi, L0, H0);
  swap32(U[2][1], U[3][1], hi, L1, H1);
  pf1 = __builtin_bit_cast(bf16x8, (u32x4){L0, L1, H0, H1});
}

__global__ __launch_bounds__(256, 4) void attn_mfma(
    const unsigned short* __restrict__ Qb, const unsigned short* __restrict__ Kb,
    const unsigned short* __restrict__ VTb, unsigned short* __restrict__ Ob)
{
  __shared__ unsigned short Ksm[64 * 64];   // [key][d], chunk-XOR-swizzled rows
  __shared__ unsigned short VTsm[64 * 64];  // [d][key], chunk-XOR-swizzled rows

  const int bh = blockIdx.x;            // 0..63 (x-major: same bh -> one XCD)
  const int qblk = 15 - blockIdx.y;     // reversed: co-resident blocks equal-duration
  const int b = bh >> 4, h = bh & 15;
  const int tid = threadIdx.x;
  const int w = tid >> 6, lane = tid & 63;
  const int lq = lane & 31, hi = lane >> 5;
  const int qw0 = qblk * 128 + w * 32;  // this wave's 32 q-rows
  const int tq = qw0 + lq;

  const unsigned short* Kp  = Kb  + (size_t)bh * TT * DH;
  const unsigned short* VTp = VTb + (size_t)bh * DH * TT;

  // Q fragments (B-operand: col=lane&31=q, k=d=(hi*8+j)+16c), hoisted
  bf16x8 qf[4];
  {
    const unsigned short* qp = Qb + ((size_t)bh * TT + tq) * DH + hi * 8;
    #pragma unroll
    for (int c = 0; c < 4; ++c) qf[c] = *(const bf16x8*)(qp + c * 16);
  }

  f32x16 acc[2];
  #pragma unroll
  for (int dt = 0; dt < 2; ++dt)
    #pragma unroll
    for (int r = 0; r < 16; ++r) acc[dt][r] = 0.f;
  float ls = 0.f;

  char* Kc = (char*)Ksm;
  char* Vc = (char*)VTsm;

  // Staging via global_load_lds with pre-swizzled source (linear LDS dest).
  const int srow_in = (lane >> 3);               // 0..7
  const int schunk = (lane & 7) ^ (srow_in & 7); // source chunk
  const int sdoff = w * 2048 + lane * 16;        // dest byte offset

  const int ntiles = qblk * 2 + 2;
  for (int tile = 0; tile < ntiles; ++tile) {
    const int kv0 = tile * 64;
    __syncthreads();
    {
      const unsigned short* kg = Kp + (size_t)(kv0 + w * 16 + srow_in) * DH + schunk * 8;
      gload_lds16(kg, Kc + sdoff);
      gload_lds16(kg + 8 * DH, Kc + sdoff + 1024);
      const unsigned short* vg = VTp + (size_t)(w * 16 + srow_in) * TT + kv0 + schunk * 8;
      gload_lds16(vg, Vc + sdoff);
      gload_lds16(vg + 8 * TT, Vc + sdoff + 1024);
    }
    __syncthreads();

    // ---- both QK^T subtiles issued back-to-back: SM(0)'s VALU then overlaps
    //      QK(1)'s in-flight MFMAs. Accumulation order (ls, acc) identical to
    //      the sequential version -> bitwise-identical output.
    const int ks0 = kv0, ks1 = kv0 + 32;
    const bool act0 = (ks0 <= qw0);       // wave-uniform; act1 implies act0
    const bool act1 = (ks1 <= qw0);

    f32x16 s0, s1;
    if (act0) {
      const int arow = lq;
      const int aswz = (arow & 7) << 4;
      bf16x8 kf[4];
      #pragma unroll
      for (int c = 0; c < 4; ++c)
        kf[c] = *(const bf16x8*)(Kc + ((arow * 128 + (c * 16 + hi * 8) * 2) ^ aswz));
      #pragma unroll
      for (int r = 0; r < 16; ++r) s0[r] = 0.f;
      __builtin_amdgcn_s_setprio(1);
      #pragma unroll
      for (int c = 0; c < 4; ++c)
        s0 = __builtin_amdgcn_mfma_f32_32x32x16_bf16(kf[c], qf[c], s0, 0, 0, 0);
      __builtin_amdgcn_s_setprio(0);
    }
    if (act1) {
      const int arow = 32 + lq;
      const int aswz = (arow & 7) << 4;
      bf16x8 kf[4];
      #pragma unroll
      for (int c = 0; c < 4; ++c)
        kf[c] = *(const bf16x8*)(Kc + ((arow * 128 + (c * 16 + hi * 8) * 2) ^ aswz));
      #pragma unroll
      for (int r = 0; r < 16; ++r) s1[r] = 0.f;
      __builtin_amdgcn_s_setprio(1);
      #pragma unroll
      for (int c = 0; c < 4; ++c)
        s1 = __builtin_amdgcn_mfma_f32_32x32x16_bf16(kf[c], qf[c], s1, 0, 0, 0);
      __builtin_amdgcn_s_setprio(0);
    }

    if (act0) {
      bf16x8 p0, p1;
      sm_nomax(s0, ks0 == qw0, lq, hi, ls, p0, p1);
      __builtin_amdgcn_s_setprio(1);
      #pragma unroll
      for (int kc = 0; kc < 2; ++kc) {
        bf16x8 pf = kc ? p1 : p0;
        #pragma unroll
        for (int dt = 0; dt < 2; ++dt) {
          const int vrow = dt * 32 + lq;
          bf16x8 vf = *(const bf16x8*)(Vc + ((vrow * 128 + kc * 32 + hi * 16) ^ ((vrow & 7) << 4)));
          acc[dt] = __builtin_amdgcn_mfma_f32_32x32x16_bf16(vf, pf, acc[dt], 0, 0, 0);
        }
      }
      __builtin_amdgcn_s_setprio(0);
    }
    if (act1) {
      bf16x8 p0, p1;
      sm_nomax(s1, ks1 == qw0, lq, hi, ls, p0, p1);
      __builtin_amdgcn_s_setprio(1);
      #pragma unroll
      for (int kc = 0; kc < 2; ++kc) {
        bf16x8 pf = kc ? p1 : p0;
        #pragma unroll
        for (int dt = 0; dt < 2; ++dt) {
          const int vrow = dt * 32 + lq;
          bf16x8 vf = *(const bf16x8*)(Vc + ((vrow * 128 + 64 + kc * 32 + hi * 16) ^ ((vrow & 7) << 4)));
          acc[dt] = __builtin_amdgcn_mfma_f32_32x32x16_bf16(vf, pf, acc[dt], 0, 0, 0);
        }
      }
      __builtin_amdgcn_s_setprio(0);
    }
  }

  {
    const float l = ls + __shfl_xor(ls, 32, 64);
    const float inv = 1.f / l;
    unsigned short* op = Ob + ((size_t)b * TT + tq) * CC + h * DH;
    #pragma unroll
    for (int dt = 0; dt < 2; ++dt)
      #pragma unroll
      for (int r = 0; r < 16; ++r)
        op[dt * 32 + crow(r, hi)] = f2b(acc[dt][r] * inv);
  }
}

extern "C" void kernel_launch(void* const* d_in, const int* in_sizes, int n_in,
                              void* d_out, int out_size, void* d_ws, size_t ws_size,
                              hipStream_t stream) {
  const float* x     = (const float*)d_in[0];
  const float* Wq    = (const float*)d_in[1];
  const float* Wk    = (const float*)d_in[2];
  const float* Wv    = (const float*)d_in[3];
  const float* Wproj = (const float*)d_in[4];

  unsigned short* xb  = (unsigned short*)d_ws;                 // [8192][1024] A-matrix
  unsigned short* Wt  = xb + (size_t)BT * CC;                  // [3072][1024]
  unsigned short* WpT = Wt + (size_t)NQKV * CC;                // [1024][1024]
  unsigned short* QKV = WpT + (size_t)CC * CC;                 // Q,K in [B][H][T][DH]; V slot holds VT
  unsigned short* Ob  = QKV + (size_t)3 * BB * HH * TT * DH;   // [8192][1024]
  unsigned short* Qb  = QKV;
  unsigned short* Kb  = QKV + (size_t)BB * HH * TT * DH;
  unsigned short* VT  = Kb + (size_t)BB * HH * TT * DH;        // V^T [bh][DH][T], written by gemm<0>

  prep_all<<<8192, 256, 0, stream>>>(x, Wq, Wk, Wv, Wproj, xb, Wt, WpT);
  mfma_gemm<0><<<dim3(64, 24), 256, 0, stream>>>(xb, Wt, QKV, VT, BT, NQKV, CC);
  attn_mfma<<<dim3(64, 16), 256, 0, stream>>>(Qb, Kb, VT, Ob);
  mfma_gemm<1><<<dim3(64, 8), 256, 0, stream>>>(Ob, WpT, d_out, nullptr, BT, CC, CC);
}

// Round 25
// 164.131 us; speedup vs baseline: 1.0488x; 1.0488x over previous
//
#include <hip/hip_runtime.h>
#include <math.h>
#include <stdint.h>

#define BB 4
#define TT 2048
#define CC 1024
#define HH 16
#define DH 64
#define BT (BB*TT)      // 8192
#define NQKV (3*HH*DH)  // 3072

typedef __attribute__((ext_vector_type(8))) __bf16 bf16x8;
typedef __attribute__((ext_vector_type(4))) float f32x4;
typedef __attribute__((ext_vector_type(16))) float f32x16;
typedef __attribute__((ext_vector_type(8))) unsigned short u16x8;
typedef __attribute__((ext_vector_type(4))) unsigned short u16x4;
typedef __attribute__((ext_vector_type(4))) unsigned int u32x4;

__device__ __forceinline__ unsigned short f2b(float f) {
  union { float f; unsigned u; } v; v.f = f;
  unsigned r = v.u + 0x7fffu + ((v.u >> 16) & 1u);
  return (unsigned short)(r >> 16);
}

__device__ __forceinline__ void gload_lds16(const void* g, void* lds) {
  __builtin_amdgcn_global_load_lds(
      (const __attribute__((address_space(1))) void*)(uintptr_t)g,
      (__attribute__((address_space(3))) void*)(uintptr_t)lds, 16, 0, 0);
}

__device__ __forceinline__ unsigned cvtpk_bf16(float lo, float hi) {
  unsigned r;
  asm("v_cvt_pk_bf16_f32 %0, %1, %2" : "=v"(r) : "v"(lo), "v"(hi));
  return r;
}

__device__ __forceinline__ float fexp2(float x) {
#if __has_builtin(__builtin_amdgcn_exp2f)
  return __builtin_amdgcn_exp2f(x);
#else
  float r; asm("v_exp_f32 %0, %1" : "=v"(r) : "v"(x)); return r;
#endif
}

// ---------- merged prep: x->bf16, QKV weight transpose, Wproj transpose ----------
__global__ __launch_bounds__(256) void prep_all(
    const float* __restrict__ x,
    const float* __restrict__ Wq, const float* __restrict__ Wk, const float* __restrict__ Wv,
    const float* __restrict__ Wproj,
    unsigned short* __restrict__ xb, unsigned short* __restrict__ Wt,
    unsigned short* __restrict__ WpT)
{
  __shared__ float tile[32][33];
  const int bid = blockIdx.x;
  const int tid = threadIdx.x;

  if (bid < 4096) {                       // ---- cvt_bf16: x -> xb
    int i = (bid * 256 + tid) * 8;
    float4 a = *(const float4*)(x + i);
    float4 b = *(const float4*)(x + i + 4);
    u16x8 pk;
    pk[0] = f2b(a.x); pk[1] = f2b(a.y); pk[2] = f2b(a.z); pk[3] = f2b(a.w);
    pk[4] = f2b(b.x); pk[5] = f2b(b.y); pk[6] = f2b(b.z); pk[7] = f2b(b.w);
    *(u16x8*)(xb + i) = pk;
    return;
  }

  const int tx = tid & 31, ty = tid >> 5;  // flattened 32x8
  if (bid < 7168) {                        // ---- QKV transpose: [16][C][DH]x3 -> [48][DH][C]
    const int id = bid - 4096;             // = z*64 + ry*2 + rx
    const int rx = id & 1, ry = (id >> 1) & 31, z = id >> 6;
    const float* in = (z < 16 ? Wq : (z < 32 ? Wk : Wv)) + (size_t)(z & 15) * CC * DH;
    unsigned short* o = Wt + (size_t)z * CC * DH;
    const int r0 = ry * 32, c0 = rx * 32;
    #pragma unroll
    for (int i = 0; i < 32; i += 8)
      tile[ty + i][tx] = in[(size_t)(r0 + ty + i) * DH + c0 + tx];
    __syncthreads();
    #pragma unroll
    for (int i = 0; i < 32; i += 8)
      o[(size_t)(c0 + ty + i) * CC + r0 + tx] = f2b(tile[tx][ty + i]);
    return;
  }

  {                                        // ---- Wproj transpose: [C][C] -> [C][C]^T
    const int id = bid - 7168;             // = ry*32 + rx
    const int rx = id & 31, ry = id >> 5;
    const int r0 = ry * 32, c0 = rx * 32;
    #pragma unroll
    for (int i = 0; i < 32; i += 8)
      tile[ty + i][tx] = Wproj[(size_t)(r0 + ty + i) * CC + c0 + tx];
    __syncthreads();
    #pragma unroll
    for (int i = 0; i < 32; i += 8)
      WpT[(size_t)(c0 + ty + i) * CC + r0 + tx] = f2b(tile[tx][ty + i]);
  }
}

// ---------- bf16 MFMA GEMM (BK=64, XOR-swizzled LDS, single-barrier dbuf) ----------
// Locked-in structure (r22, best verified). Lessons:
//  - r20: 64KB LDS / 2 blocks/CU is the L2-dictated optimum (co-resident 8x8
//    tile rectangle = 4MB = per-XCD L2; 4 blocks/CU thrashes, 9x slower).
//  - r23: counted-vmcnt graft on this 2-barrier structure is NULL (guide m131):
//    implicit wave-level overlap at 2 blocks/CU already hides the drain.
//    Path beyond ~33% MfmaUtil is the full 8-phase co-designed schedule.
template<int MODE>
__global__ __launch_bounds__(256) void mfma_gemm(
    const unsigned short* __restrict__ A,
    const unsigned short* __restrict__ Bt,
    void* __restrict__ Cout, unsigned short* __restrict__ VTout,
    int M, int N, int K)
{
  __shared__ unsigned short As[2 * 128 * 64];   // 32 KB (2 buffers)
  __shared__ unsigned short Bs[2 * 128 * 64];   // 32 KB
  const int tid = threadIdx.x;
  const int l = tid & 63, w = tid >> 6;
  const int wr = w >> 1, wc = w & 1;

  const int wid = blockIdx.y * gridDim.x + blockIdx.x;
  const int local = wid >> 3;
  const int rt = (wid & 7) * 8 + (local & 7);
  const int ct = local >> 3;
  const long row0 = (long)rt * 128, col0 = (long)ct * 128;

  const bool SWAP = (MODE == 1) || (ct < 16);   // block-uniform

  const int srowA = w * 32 + (l >> 3);
  const int schunk = (l & 7) ^ ((l >> 3) & 7);
  const unsigned short* Ap = A + (row0 + srowA) * (long)K + schunk * 8;
  const unsigned short* Bp = Bt + (col0 + srowA) * (long)K + schunk * 8;
  const size_t woff = (size_t)w * 4096;

  f32x4 acc[4][4];
  #pragma unroll
  for (int i = 0; i < 4; ++i)
    #pragma unroll
    for (int j = 0; j < 4; ++j) acc[i][j] = (f32x4){0.f, 0.f, 0.f, 0.f};

  const int fr = l & 15, fg = l >> 4;
  const int fswz = fr & 7;

  // prologue: stage K-tile 0 into buffer 0
  #pragma unroll
  for (int i = 0; i < 4; ++i) {
    gload_lds16(Ap + (size_t)i * 8 * K, (char*)As + woff + i * 1024);
    gload_lds16(Bp + (size_t)i * 8 * K, (char*)Bs + woff + i * 1024);
  }
  __syncthreads();

  const int NT = K >> 6;
  for (int kt = 0; kt < NT; ++kt) {
    const int cur = kt & 1;
    if (kt + 1 < NT) {                       // prefetch next tile into buf^1
      const long k0 = (long)(kt + 1) * 64;
      char* Ad = (char*)As + (cur ^ 1) * 16384 + woff;
      char* Bd = (char*)Bs + (cur ^ 1) * 16384 + woff;
      #pragma unroll
      for (int i = 0; i < 4; ++i) {
        gload_lds16(Ap + (size_t)i * 8 * K + k0, Ad + i * 1024);
        gload_lds16(Bp + (size_t)i * 8 * K + k0, Bd + i * 1024);
      }
    }
    const char* aB = (const char*)As + cur * 16384;
    const char* bB = (const char*)Bs + cur * 16384;
    #pragma unroll
    for (int kk = 0; kk < 2; ++kk) {
      bf16x8 af[4], bfr[4];
      #pragma unroll
      for (int m = 0; m < 4; ++m)
        af[m] = *(const bf16x8*)(aB + (wr * 64 + m * 16 + fr) * 128 + (((fg + kk * 4) ^ fswz) << 4));
      #pragma unroll
      for (int n = 0; n < 4; ++n)
        bfr[n] = *(const bf16x8*)(bB + (wc * 64 + n * 16 + fr) * 128 + (((fg + kk * 4) ^ fswz) << 4));
      if (SWAP) {
        #pragma unroll
        for (int m = 0; m < 4; ++m)
          #pragma unroll
          for (int n = 0; n < 4; ++n)
            acc[m][n] = __builtin_amdgcn_mfma_f32_16x16x32_bf16(bfr[n], af[m], acc[m][n], 0, 0, 0);
      } else {
        #pragma unroll
        for (int m = 0; m < 4; ++m)
          #pragma unroll
          for (int n = 0; n < 4; ++n)
            acc[m][n] = __builtin_amdgcn_mfma_f32_16x16x32_bf16(af[m], bfr[n], acc[m][n], 0, 0, 0);
      }
    }
    __syncthreads();   // publish prefetched buf^1; protect reuse of buf cur
  }

  const int fq = l >> 4;
  if (MODE == 1) {
    #pragma unroll
    for (int m = 0; m < 4; ++m) {
      long grow = row0 + wr * 64 + m * 16 + fr;
      #pragma unroll
      for (int n = 0; n < 4; ++n) {
        long gcol0 = col0 + wc * 64 + n * 16 + fq * 4;
        float4 v = make_float4(acc[m][n][0], acc[m][n][1], acc[m][n][2], acc[m][n][3]);
        *(float4*)&((float*)Cout)[grow * (long)N + gcol0] = v;
      }
    }
  } else if (ct < 16) {
    // Q/K, SWAP layout: reg r -> d (4 contiguous). u16x4 stores.
    #pragma unroll
    for (int m = 0; m < 4; ++m) {
      int t = (int)(row0 + wr * 64 + m * 16 + fr);
      int b = t >> 11, tt = t & 2047;
      #pragma unroll
      for (int n = 0; n < 4; ++n) {
        long gcol0 = col0 + wc * 64 + n * 16 + fq * 4;
        int which = (int)(gcol0 >> 10);
        int h = (int)((gcol0 >> 6) & 15);
        int d0 = (int)(gcol0 & 63);
        float sc = (which == 0) ? 0.04508422017f : 1.f;  // C^-0.5 * log2(e) into Q
        u16x4 pk;
        #pragma unroll
        for (int r = 0; r < 4; ++r) pk[r] = f2b(acc[m][n][r] * sc);
        *(u16x4*)&((unsigned short*)Cout)[((((size_t)which * BB + b) * HH + h) * TT + tt) * DH + d0] = pk;
      }
    }
  } else {
    // V, normal layout: reg r -> t (4 contiguous). u16x4 into VT [bh][d][t].
    #pragma unroll
    for (int m = 0; m < 4; ++m) {
      long grow0 = row0 + wr * 64 + m * 16 + fq * 4;
      int b = (int)(grow0 >> 11), t0 = (int)(grow0 & 2047);
      #pragma unroll
      for (int n = 0; n < 4; ++n) {
        long gcol = col0 + wc * 64 + n * 16 + fr;
        int h = (int)((gcol >> 6) & 15);
        int d = (int)(gcol & 63);
        u16x4 pk;
        #pragma unroll
        for (int r = 0; r < 4; ++r) pk[r] = f2b(acc[m][n][r]);
        *(u16x4*)&VTout[((size_t)(b * HH + h) * DH + d) * TT + t0] = pk;
      }
    }
  }
}

// ---------- MFMA flash attention: unpaired q-tiles, reversed dispatch ----------
// Locked-in structure (r22 best). Lessons: r24 two-S-tile ILP reorder spilled
// under the (256,4) VGPR cap (WRITE 16->45MB scratch) and regressed; r17
// conflict-free swizzle was null (conflicts hidden by latency slack); r18
// sum-balanced dispatch regressed (co-resident blocks must be equal-DURATION,
// which the plain reversed order provides).
__device__ __forceinline__ int crow(int r, int hi) { return (r & 3) + 8 * (r >> 2) + 4 * hi; }

__device__ __forceinline__ void swap32(unsigned a, unsigned b, int hi,
                                       unsigned& L, unsigned& H) {
#if __has_builtin(__builtin_amdgcn_permlane32_swap)
  typedef unsigned uint2v __attribute__((ext_vector_type(2)));
  uint2v rr = __builtin_amdgcn_permlane32_swap(a, b, false, false);
  L = rr[0]; H = rr[1];
#else
  unsigned ax = __shfl_xor((int)a, 32, 64), bx = __shfl_xor((int)b, 32, 64);
  L = hi ? bx : a;
  H = hi ? b : ax;
#endif
}

// no-max softmax: P = exp2(S) (log2e pre-folded into Q), lane-local l accumulation.
__device__ __forceinline__ void sm_nomax(const f32x16& s, bool diag, int lq, int hi,
                                         float& lsum, bf16x8& pf0, bf16x8& pf1) {
  float p[16];
  #pragma unroll
  for (int r = 0; r < 16; ++r) {
    float e = fexp2(s[r]);
    if (diag && (crow(r, hi) > lq)) e = 0.f;
    p[r] = e;
  }
  float t[8];
  #pragma unroll
  for (int r = 0; r < 8; ++r) t[r] = p[r] + p[r + 8];
  #pragma unroll
  for (int r = 0; r < 4; ++r) t[r] = t[r] + t[r + 4];
  lsum += ((t[0] + t[1]) + (t[2] + t[3]));

  unsigned U[4][2];
  #pragma unroll
  for (int g = 0; g < 4; ++g) {
    U[g][0] = cvtpk_bf16(p[4 * g + 0], p[4 * g + 1]);
    U[g][1] = cvtpk_bf16(p[4 * g + 2], p[4 * g + 3]);
  }
  unsigned L0, H0, L1, H1;
  swap32(U[0][0], U[1][0], hi, L0, H0);
  swap32(U[0][1], U[1][1], hi, L1, H1);
  pf0 = __builtin_bit_cast(bf16x8, (u32x4){L0, L1, H0, H1});
  swap32(U[2][0], U[3][0], hi, L0, H0);
  swap32(U[2][1], U[3][1], hi, L1, H1);
  pf1 = __builtin_bit_cast(bf16x8, (u32x4){L0, L1, H0, H1});
}

__global__ __launch_bounds__(256, 4) void attn_mfma(
    const unsigned short* __restrict__ Qb, const unsigned short* __restrict__ Kb,
    const unsigned short* __restrict__ VTb, unsigned short* __restrict__ Ob)
{
  __shared__ unsigned short Ksm[64 * 64];   // [key][d], chunk-XOR-swizzled rows
  __shared__ unsigned short VTsm[64 * 64];  // [d][key], chunk-XOR-swizzled rows

  const int bh = blockIdx.x;            // 0..63 (x-major: same bh -> one XCD)
  const int qblk = 15 - blockIdx.y;     // reversed: co-resident blocks equal-duration
  const int b = bh >> 4, h = bh & 15;
  const int tid = threadIdx.x;
  const int w = tid >> 6, lane = tid & 63;
  const int lq = lane & 31, hi = lane >> 5;
  const int qw0 = qblk * 128 + w * 32;  // this wave's 32 q-rows
  const int tq = qw0 + lq;

  const unsigned short* Kp  = Kb  + (size_t)bh * TT * DH;
  const unsigned short* VTp = VTb + (size_t)bh * DH * TT;

  // Q fragments (B-operand: col=lane&31=q, k=d=(hi*8+j)+16c), hoisted
  bf16x8 qf[4];
  {
    const unsigned short* qp = Qb + ((size_t)bh * TT + tq) * DH + hi * 8;
    #pragma unroll
    for (int c = 0; c < 4; ++c) qf[c] = *(const bf16x8*)(qp + c * 16);
  }

  f32x16 acc[2];
  #pragma unroll
  for (int dt = 0; dt < 2; ++dt)
    #pragma unroll
    for (int r = 0; r < 16; ++r) acc[dt][r] = 0.f;
  float ls = 0.f;

  char* Kc = (char*)Ksm;
  char* Vc = (char*)VTsm;

  // Staging via global_load_lds with pre-swizzled source (linear LDS dest).
  const int srow_in = (lane >> 3);               // 0..7
  const int schunk = (lane & 7) ^ (srow_in & 7); // source chunk
  const int sdoff = w * 2048 + lane * 16;        // dest byte offset

  const int ntiles = qblk * 2 + 2;
  for (int tile = 0; tile < ntiles; ++tile) {
    const int kv0 = tile * 64;
    __syncthreads();
    {
      const unsigned short* kg = Kp + (size_t)(kv0 + w * 16 + srow_in) * DH + schunk * 8;
      gload_lds16(kg, Kc + sdoff);
      gload_lds16(kg + 8 * DH, Kc + sdoff + 1024);
      const unsigned short* vg = VTp + (size_t)(w * 16 + srow_in) * TT + kv0 + schunk * 8;
      gload_lds16(vg, Vc + sdoff);
      gload_lds16(vg + 8 * TT, Vc + sdoff + 1024);
    }
    __syncthreads();

    #pragma unroll
    for (int sub = 0; sub < 2; ++sub) {
      const int ks = kv0 + sub * 32;
      if (ks > qw0) break;           // wave-uniform

      // ---- K fragments
      const int arow = sub * 32 + lq;
      const int aswz = (arow & 7) << 4;
      bf16x8 kf[4];
      #pragma unroll
      for (int c = 0; c < 4; ++c)
        kf[c] = *(const bf16x8*)(Kc + ((arow * 128 + (c * 16 + hi * 8) * 2) ^ aswz));

      // ---- S^T = K · Q^T
      f32x16 s;
      #pragma unroll
      for (int r = 0; r < 16; ++r) s[r] = 0.f;
      __builtin_amdgcn_s_setprio(1);
      #pragma unroll
      for (int c = 0; c < 4; ++c)
        s = __builtin_amdgcn_mfma_f32_32x32x16_bf16(kf[c], qf[c], s, 0, 0, 0);
      __builtin_amdgcn_s_setprio(0);
      bf16x8 p0, p1;
      sm_nomax(s, ks == qw0, lq, hi, ls, p0, p1);

      // ---- PV: O^T += V^T · P^T
      __builtin_amdgcn_s_setprio(1);
      #pragma unroll
      for (int kc = 0; kc < 2; ++kc) {
        bf16x8 pf = kc ? p1 : p0;
        #pragma unroll
        for (int dt = 0; dt < 2; ++dt) {
          const int vrow = dt * 32 + lq;
          bf16x8 vf = *(const bf16x8*)(Vc + ((vrow * 128 + sub * 64 + kc * 32 + hi * 16) ^ ((vrow & 7) << 4)));
          acc[dt] = __builtin_amdgcn_mfma_f32_32x32x16_bf16(vf, pf, acc[dt], 0, 0, 0);
        }
      }
      __builtin_amdgcn_s_setprio(0);
    }
  }

  {
    const float l = ls + __shfl_xor(ls, 32, 64);
    const float inv = 1.f / l;
    unsigned short* op = Ob + ((size_t)b * TT + tq) * CC + h * DH;
    #pragma unroll
    for (int dt = 0; dt < 2; ++dt)
      #pragma unroll
      for (int r = 0; r < 16; ++r)
        op[dt * 32 + crow(r, hi)] = f2b(acc[dt][r] * inv);
  }
}

extern "C" void kernel_launch(void* const* d_in, const int* in_sizes, int n_in,
                              void* d_out, int out_size, void* d_ws, size_t ws_size,
                              hipStream_t stream) {
  const float* x     = (const float*)d_in[0];
  const float* Wq    = (const float*)d_in[1];
  const float* Wk    = (const float*)d_in[2];
  const float* Wv    = (const float*)d_in[3];
  const float* Wproj = (const float*)d_in[4];

  unsigned short* xb  = (unsigned short*)d_ws;                 // [8192][1024] A-matrix
  unsigned short* Wt  = xb + (size_t)BT * CC;                  // [3072][1024]
  unsigned short* WpT = Wt + (size_t)NQKV * CC;                // [1024][1024]
  unsigned short* QKV = WpT + (size_t)CC * CC;                 // Q,K in [B][H][T][DH]; V slot holds VT
  unsigned short* Ob  = QKV + (size_t)3 * BB * HH * TT * DH;   // [8192][1024]
  unsigned short* Qb  = QKV;
  unsigned short* Kb  = QKV + (size_t)BB * HH * TT * DH;
  unsigned short* VT  = Kb + (size_t)BB * HH * TT * DH;        // V^T [bh][DH][T], written by gemm<0>

  prep_all<<<8192, 256, 0, stream>>>(x, Wq, Wk, Wv, Wproj, xb, Wt, WpT);
  mfma_gemm<0><<<dim3(64, 24), 256, 0, stream>>>(xb, Wt, QKV, VT, BT, NQKV, CC);
  attn_mfma<<<dim3(64, 16), 256, 0, stream>>>(Qb, Kb, VT, Ob);
  mfma_gemm<1><<<dim3(64, 8), 256, 0, stream>>>(Ob, WpT, d_out, nullptr, BT, CC, CC);
}

// Round 26
// 161.667 us; speedup vs baseline: 1.0648x; 1.0152x over previous
//
#include <hip/hip_runtime.h>
#include <math.h>
#include <stdint.h>

#define BB 4
#define TT 2048
#define CC 1024
#define HH 16
#define DH 64
#define BT (BB*TT)      // 8192
#define NQKV (3*HH*DH)  // 3072

typedef __attribute__((ext_vector_type(8))) __bf16 bf16x8;
typedef __attribute__((ext_vector_type(4))) float f32x4;
typedef __attribute__((ext_vector_type(16))) float f32x16;
typedef __attribute__((ext_vector_type(8))) unsigned short u16x8;
typedef __attribute__((ext_vector_type(4))) unsigned short u16x4;
typedef __attribute__((ext_vector_type(4))) unsigned int u32x4;

__device__ __forceinline__ unsigned short f2b(float f) {
  union { float f; unsigned u; } v; v.f = f;
  unsigned r = v.u + 0x7fffu + ((v.u >> 16) & 1u);
  return (unsigned short)(r >> 16);
}

__device__ __forceinline__ void gload_lds16(const void* g, void* lds) {
  __builtin_amdgcn_global_load_lds(
      (const __attribute__((address_space(1))) void*)(uintptr_t)g,
      (__attribute__((address_space(3))) void*)(uintptr_t)lds, 16, 0, 0);
}

__device__ __forceinline__ unsigned cvtpk_bf16(float lo, float hi) {
  unsigned r;
  asm("v_cvt_pk_bf16_f32 %0, %1, %2" : "=v"(r) : "v"(lo), "v"(hi));
  return r;
}

__device__ __forceinline__ float fexp2(float x) {
#if __has_builtin(__builtin_amdgcn_exp2f)
  return __builtin_amdgcn_exp2f(x);
#else
  float r; asm("v_exp_f32 %0, %1" : "=v"(r) : "v"(x)); return r;
#endif
}

// ---------- merged prep: x->bf16, QKV weight transpose, Wproj transpose ----------
__global__ __launch_bounds__(256) void prep_all(
    const float* __restrict__ x,
    const float* __restrict__ Wq, const float* __restrict__ Wk, const float* __restrict__ Wv,
    const float* __restrict__ Wproj,
    unsigned short* __restrict__ xb, unsigned short* __restrict__ Wt,
    unsigned short* __restrict__ WpT)
{
  __shared__ float tile[32][33];
  const int bid = blockIdx.x;
  const int tid = threadIdx.x;

  if (bid < 4096) {                       // ---- cvt_bf16: x -> xb
    int i = (bid * 256 + tid) * 8;
    float4 a = *(const float4*)(x + i);
    float4 b = *(const float4*)(x + i + 4);
    u16x8 pk;
    pk[0] = f2b(a.x); pk[1] = f2b(a.y); pk[2] = f2b(a.z); pk[3] = f2b(a.w);
    pk[4] = f2b(b.x); pk[5] = f2b(b.y); pk[6] = f2b(b.z); pk[7] = f2b(b.w);
    *(u16x8*)(xb + i) = pk;
    return;
  }

  const int tx = tid & 31, ty = tid >> 5;  // flattened 32x8
  if (bid < 7168) {                        // ---- QKV transpose: [16][C][DH]x3 -> [48][DH][C]
    const int id = bid - 4096;             // = z*64 + ry*2 + rx
    const int rx = id & 1, ry = (id >> 1) & 31, z = id >> 6;
    const float* in = (z < 16 ? Wq : (z < 32 ? Wk : Wv)) + (size_t)(z & 15) * CC * DH;
    unsigned short* o = Wt + (size_t)z * CC * DH;
    const int r0 = ry * 32, c0 = rx * 32;
    #pragma unroll
    for (int i = 0; i < 32; i += 8)
      tile[ty + i][tx] = in[(size_t)(r0 + ty + i) * DH + c0 + tx];
    __syncthreads();
    #pragma unroll
    for (int i = 0; i < 32; i += 8)
      o[(size_t)(c0 + ty + i) * CC + r0 + tx] = f2b(tile[tx][ty + i]);
    return;
  }

  {                                        // ---- Wproj transpose: [C][C] -> [C][C]^T
    const int id = bid - 7168;             // = ry*32 + rx
    const int rx = id & 31, ry = id >> 5;
    const int r0 = ry * 32, c0 = rx * 32;
    #pragma unroll
    for (int i = 0; i < 32; i += 8)
      tile[ty + i][tx] = Wproj[(size_t)(r0 + ty + i) * CC + c0 + tx];
    __syncthreads();
    #pragma unroll
    for (int i = 0; i < 32; i += 8)
      WpT[(size_t)(c0 + ty + i) * CC + r0 + tx] = f2b(tile[tx][ty + i]);
  }
}

// ---------- bf16 MFMA GEMM (BK=64, XOR-swizzled LDS, single-barrier dbuf) ----------
// Locked-in structure (r22 best). r20: 2 blocks/CU is L2-dictated optimum.
// r23: counted-vmcnt graft NULL on this 2-barrier structure (guide m131).
template<int MODE>
__global__ __launch_bounds__(256) void mfma_gemm(
    const unsigned short* __restrict__ A,
    const unsigned short* __restrict__ Bt,
    void* __restrict__ Cout, unsigned short* __restrict__ VTout,
    int M, int N, int K)
{
  __shared__ unsigned short As[2 * 128 * 64];   // 32 KB (2 buffers)
  __shared__ unsigned short Bs[2 * 128 * 64];   // 32 KB
  const int tid = threadIdx.x;
  const int l = tid & 63, w = tid >> 6;
  const int wr = w >> 1, wc = w & 1;

  const int wid = blockIdx.y * gridDim.x + blockIdx.x;
  const int local = wid >> 3;
  const int rt = (wid & 7) * 8 + (local & 7);
  const int ct = local >> 3;
  const long row0 = (long)rt * 128, col0 = (long)ct * 128;

  const bool SWAP = (MODE == 1) || (ct < 16);   // block-uniform

  const int srowA = w * 32 + (l >> 3);
  const int schunk = (l & 7) ^ ((l >> 3) & 7);
  const unsigned short* Ap = A + (row0 + srowA) * (long)K + schunk * 8;
  const unsigned short* Bp = Bt + (col0 + srowA) * (long)K + schunk * 8;
  const size_t woff = (size_t)w * 4096;

  f32x4 acc[4][4];
  #pragma unroll
  for (int i = 0; i < 4; ++i)
    #pragma unroll
    for (int j = 0; j < 4; ++j) acc[i][j] = (f32x4){0.f, 0.f, 0.f, 0.f};

  const int fr = l & 15, fg = l >> 4;
  const int fswz = fr & 7;

  // prologue: stage K-tile 0 into buffer 0
  #pragma unroll
  for (int i = 0; i < 4; ++i) {
    gload_lds16(Ap + (size_t)i * 8 * K, (char*)As + woff + i * 1024);
    gload_lds16(Bp + (size_t)i * 8 * K, (char*)Bs + woff + i * 1024);
  }
  __syncthreads();

  const int NT = K >> 6;
  for (int kt = 0; kt < NT; ++kt) {
    const int cur = kt & 1;
    if (kt + 1 < NT) {                       // prefetch next tile into buf^1
      const long k0 = (long)(kt + 1) * 64;
      char* Ad = (char*)As + (cur ^ 1) * 16384 + woff;
      char* Bd = (char*)Bs + (cur ^ 1) * 16384 + woff;
      #pragma unroll
      for (int i = 0; i < 4; ++i) {
        gload_lds16(Ap + (size_t)i * 8 * K + k0, Ad + i * 1024);
        gload_lds16(Bp + (size_t)i * 8 * K + k0, Bd + i * 1024);
      }
    }
    const char* aB = (const char*)As + cur * 16384;
    const char* bB = (const char*)Bs + cur * 16384;
    #pragma unroll
    for (int kk = 0; kk < 2; ++kk) {
      bf16x8 af[4], bfr[4];
      #pragma unroll
      for (int m = 0; m < 4; ++m)
        af[m] = *(const bf16x8*)(aB + (wr * 64 + m * 16 + fr) * 128 + (((fg + kk * 4) ^ fswz) << 4));
      #pragma unroll
      for (int n = 0; n < 4; ++n)
        bfr[n] = *(const bf16x8*)(bB + (wc * 64 + n * 16 + fr) * 128 + (((fg + kk * 4) ^ fswz) << 4));
      if (SWAP) {
        #pragma unroll
        for (int m = 0; m < 4; ++m)
          #pragma unroll
          for (int n = 0; n < 4; ++n)
            acc[m][n] = __builtin_amdgcn_mfma_f32_16x16x32_bf16(bfr[n], af[m], acc[m][n], 0, 0, 0);
      } else {
        #pragma unroll
        for (int m = 0; m < 4; ++m)
          #pragma unroll
          for (int n = 0; n < 4; ++n)
            acc[m][n] = __builtin_amdgcn_mfma_f32_16x16x32_bf16(af[m], bfr[n], acc[m][n], 0, 0, 0);
      }
    }
    __syncthreads();   // publish prefetched buf^1; protect reuse of buf cur
  }

  const int fq = l >> 4;
  if (MODE == 1) {
    #pragma unroll
    for (int m = 0; m < 4; ++m) {
      long grow = row0 + wr * 64 + m * 16 + fr;
      #pragma unroll
      for (int n = 0; n < 4; ++n) {
        long gcol0 = col0 + wc * 64 + n * 16 + fq * 4;
        float4 v = make_float4(acc[m][n][0], acc[m][n][1], acc[m][n][2], acc[m][n][3]);
        *(float4*)&((float*)Cout)[grow * (long)N + gcol0] = v;
      }
    }
  } else if (ct < 16) {
    // Q/K, SWAP layout: reg r -> d (4 contiguous). u16x4 stores.
    #pragma unroll
    for (int m = 0; m < 4; ++m) {
      int t = (int)(row0 + wr * 64 + m * 16 + fr);
      int b = t >> 11, tt = t & 2047;
      #pragma unroll
      for (int n = 0; n < 4; ++n) {
        long gcol0 = col0 + wc * 64 + n * 16 + fq * 4;
        int which = (int)(gcol0 >> 10);
        int h = (int)((gcol0 >> 6) & 15);
        int d0 = (int)(gcol0 & 63);
        float sc = (which == 0) ? 0.04508422017f : 1.f;  // C^-0.5 * log2(e) into Q
        u16x4 pk;
        #pragma unroll
        for (int r = 0; r < 4; ++r) pk[r] = f2b(acc[m][n][r] * sc);
        *(u16x4*)&((unsigned short*)Cout)[((((size_t)which * BB + b) * HH + h) * TT + tt) * DH + d0] = pk;
      }
    }
  } else {
    // V, normal layout: reg r -> t (4 contiguous). u16x4 into VT [bh][d][t].
    #pragma unroll
    for (int m = 0; m < 4; ++m) {
      long grow0 = row0 + wr * 64 + m * 16 + fq * 4;
      int b = (int)(grow0 >> 11), t0 = (int)(grow0 & 2047);
      #pragma unroll
      for (int n = 0; n < 4; ++n) {
        long gcol = col0 + wc * 64 + n * 16 + fr;
        int h = (int)((gcol >> 6) & 15);
        int d = (int)(gcol & 63);
        u16x4 pk;
        #pragma unroll
        for (int r = 0; r < 4; ++r) pk[r] = f2b(acc[m][n][r]);
        *(u16x4*)&VTout[((size_t)(b * HH + h) * DH + d) * TT + t0] = pk;
      }
    }
  }
}

// ---------- MFMA flash attention: 128-key KV tiles (halved barrier count) ----------
__device__ __forceinline__ int crow(int r, int hi) { return (r & 3) + 8 * (r >> 2) + 4 * hi; }

__device__ __forceinline__ void swap32(unsigned a, unsigned b, int hi,
                                       unsigned& L, unsigned& H) {
#if __has_builtin(__builtin_amdgcn_permlane32_swap)
  typedef unsigned uint2v __attribute__((ext_vector_type(2)));
  uint2v rr = __builtin_amdgcn_permlane32_swap(a, b, false, false);
  L = rr[0]; H = rr[1];
#else
  unsigned ax = __shfl_xor((int)a, 32, 64), bx = __shfl_xor((int)b, 32, 64);
  L = hi ? bx : a;
  H = hi ? b : ax;
#endif
}

// no-max softmax: P = exp2(S) (log2e pre-folded into Q), lane-local l accumulation.
__device__ __forceinline__ void sm_nomax(const f32x16& s, bool diag, int lq, int hi,
                                         float& lsum, bf16x8& pf0, bf16x8& pf1) {
  float p[16];
  #pragma unroll
  for (int r = 0; r < 16; ++r) {
    float e = fexp2(s[r]);
    if (diag && (crow(r, hi) > lq)) e = 0.f;
    p[r] = e;
  }
  float t[8];
  #pragma unroll
  for (int r = 0; r < 8; ++r) t[r] = p[r] + p[r + 8];
  #pragma unroll
  for (int r = 0; r < 4; ++r) t[r] = t[r] + t[r + 4];
  lsum += ((t[0] + t[1]) + (t[2] + t[3]));

  unsigned U[4][2];
  #pragma unroll
  for (int g = 0; g < 4; ++g) {
    U[g][0] = cvtpk_bf16(p[4 * g + 0], p[4 * g + 1]);
    U[g][1] = cvtpk_bf16(p[4 * g + 2], p[4 * g + 3]);
  }
  unsigned L0, H0, L1, H1;
  swap32(U[0][0], U[1][0], hi, L0, H0);
  swap32(U[0][1], U[1][1], hi, L1, H1);
  pf0 = __builtin_bit_cast(bf16x8, (u32x4){L0, L1, H0, H1});
  swap32(U[2][0], U[3][0], hi, L0, H0);
  swap32(U[2][1], U[3][1], hi, L1, H1);
  pf1 = __builtin_bit_cast(bf16x8, (u32x4){L0, L1, H0, H1});
}

__global__ __launch_bounds__(256, 4) void attn_mfma(
    const unsigned short* __restrict__ Qb, const unsigned short* __restrict__ Kb,
    const unsigned short* __restrict__ VTb, unsigned short* __restrict__ Ob)
{
  __shared__ unsigned short Ksm[128 * 64];   // 16KB [key][d], chunk-XOR-swizzled rows
  __shared__ unsigned short VTsm[64 * 128];  // 16KB [d][key], chunk-XOR-swizzled rows

  const int bh = blockIdx.x;            // 0..63 (x-major: same bh -> one XCD)
  const int qblk = 15 - blockIdx.y;     // reversed: co-resident blocks equal-duration
  const int b = bh >> 4, h = bh & 15;
  const int tid = threadIdx.x;
  const int w = tid >> 6, lane = tid & 63;
  const int lq = lane & 31, hi = lane >> 5;
  const int qw0 = qblk * 128 + w * 32;  // this wave's 32 q-rows
  const int tq = qw0 + lq;

  const unsigned short* Kp  = Kb  + (size_t)bh * TT * DH;
  const unsigned short* VTp = VTb + (size_t)bh * DH * TT;

  // Q fragments (B-operand: col=lane&31=q, k=d=(hi*8+j)+16c), hoisted
  bf16x8 qf[4];
  {
    const unsigned short* qp = Qb + ((size_t)bh * TT + tq) * DH + hi * 8;
    #pragma unroll
    for (int c = 0; c < 4; ++c) qf[c] = *(const bf16x8*)(qp + c * 16);
  }

  f32x16 acc[2];
  #pragma unroll
  for (int dt = 0; dt < 2; ++dt)
    #pragma unroll
    for (int r = 0; r < 16; ++r) acc[dt][r] = 0.f;
  float ls = 0.f;

  char* Kc = (char*)Ksm;
  char* Vc = (char*)VTsm;

  // K staging: instr i covers rows w*32 + i*8 + (l>>3); LDS chunk c of row r
  // holds source chunk c ^ (r&7) (r&7 == l>>3 since w*32, i*8 are mult of 8).
  const int ksrow = (lane >> 3);                  // 0..7
  const int kschunk = (lane & 7) ^ ksrow;         // pre-swizzled source chunk
  // V^T staging: rows are 256B (16 chunks). Instr i covers d-rows
  // w*16 + i*4 + (l>>4); lane writes LDS chunk l&15 from source chunk
  // (l&15) ^ (r&7), r&7 = (i*4 + (l>>4)) & 7.
  const int vrow_in = (lane >> 4);                // 0..3
  const int sdoff = w * 4096 + lane * 16;         // dest byte offset base

  const int ntiles = qblk + 1;                    // 128-key tiles
  for (int tile = 0; tile < ntiles; ++tile) {
    const int kv0 = tile * 128;
    __syncthreads();
    {
      const unsigned short* kgb = Kp + (size_t)(kv0 + w * 32 + ksrow) * DH + kschunk * 8;
      #pragma unroll
      for (int i = 0; i < 4; ++i)
        gload_lds16(kgb + (size_t)i * 8 * DH, Kc + sdoff + i * 1024);
      #pragma unroll
      for (int i = 0; i < 4; ++i) {
        const int vsc = (lane & 15) ^ ((i * 4 + vrow_in) & 7);
        const unsigned short* vg = VTp + (size_t)(w * 16 + i * 4 + vrow_in) * TT + kv0 + vsc * 8;
        gload_lds16(vg, Vc + sdoff + i * 1024);
      }
    }
    __syncthreads();

    #pragma unroll
    for (int sub = 0; sub < 4; ++sub) {
      const int ks = kv0 + sub * 32;
      if (ks > qw0) break;           // wave-uniform

      // ---- K fragments: row arow (0..127), chunk (c*2+hi) ^ (arow&7)
      const int arow = sub * 32 + lq;
      const int aswz = (arow & 7) << 4;
      bf16x8 kf[4];
      #pragma unroll
      for (int c = 0; c < 4; ++c)
        kf[c] = *(const bf16x8*)(Kc + arow * 128 + (((c * 16 + hi * 8) * 2) ^ aswz));

      // ---- S^T = K · Q^T
      f32x16 s;
      #pragma unroll
      for (int r = 0; r < 16; ++r) s[r] = 0.f;
      __builtin_amdgcn_s_setprio(1);
      #pragma unroll
      for (int c = 0; c < 4; ++c)
        s = __builtin_amdgcn_mfma_f32_32x32x16_bf16(kf[c], qf[c], s, 0, 0, 0);
      __builtin_amdgcn_s_setprio(0);
      bf16x8 p0, p1;
      sm_nomax(s, ks == qw0, lq, hi, ls, p0, p1);

      // ---- PV: O^T += V^T · P^T  (V rows 256B; chunk cx = sub*4+kc*2+hi)
      __builtin_amdgcn_s_setprio(1);
      #pragma unroll
      for (int kc = 0; kc < 2; ++kc) {
        bf16x8 pf = kc ? p1 : p0;
        #pragma unroll
        for (int dt = 0; dt < 2; ++dt) {
          const int vrow = dt * 32 + lq;
          const int cx = sub * 4 + kc * 2 + hi;
          bf16x8 vf = *(const bf16x8*)(Vc + vrow * 256 + ((cx * 16) ^ ((vrow & 7) << 4)));
          acc[dt] = __builtin_amdgcn_mfma_f32_32x32x16_bf16(vf, pf, acc[dt], 0, 0, 0);
        }
      }
      __builtin_amdgcn_s_setprio(0);
    }
  }

  {
    const float l = ls + __shfl_xor(ls, 32, 64);
    const float inv = 1.f / l;
    unsigned short* op = Ob + ((size_t)b * TT + tq) * CC + h * DH;
    #pragma unroll
    for (int dt = 0; dt < 2; ++dt)
      #pragma unroll
      for (int r = 0; r < 16; ++r)
        op[dt * 32 + crow(r, hi)] = f2b(acc[dt][r] * inv);
  }
}

extern "C" void kernel_launch(void* const* d_in, const int* in_sizes, int n_in,
                              void* d_out, int out_size, void* d_ws, size_t ws_size,
                              hipStream_t stream) {
  const float* x     = (const float*)d_in[0];
  const float* Wq    = (const float*)d_in[1];
  const float* Wk    = (const float*)d_in[2];
  const float* Wv    = (const float*)d_in[3];
  const float* Wproj = (const float*)d_in[4];

  unsigned short* xb  = (unsigned short*)d_ws;                 // [8192][1024] A-matrix
  unsigned short* Wt  = xb + (size_t)BT * CC;                  // [3072][1024]
  unsigned short* WpT = Wt + (size_t)NQKV * CC;                // [1024][1024]
  unsigned short* QKV = WpT + (size_t)CC * CC;                 // Q,K in [B][H][T][DH]; V slot holds VT
  unsigned short* Ob  = QKV + (size_t)3 * BB * HH * TT * DH;   // [8192][1024]
  unsigned short* Qb  = QKV;
  unsigned short* Kb  = QKV + (size_t)BB * HH * TT * DH;
  unsigned short* VT  = Kb + (size_t)BB * HH * TT * DH;        // V^T [bh][DH][T], written by gemm<0>

  prep_all<<<8192, 256, 0, stream>>>(x, Wq, Wk, Wv, Wproj, xb, Wt, WpT);
  mfma_gemm<0><<<dim3(64, 24), 256, 0, stream>>>(xb, Wt, QKV, VT, BT, NQKV, CC);
  attn_mfma<<<dim3(64, 16), 256, 0, stream>>>(Qb, Kb, VT, Ob);
  mfma_gemm<1><<<dim3(64, 8), 256, 0, stream>>>(Ob, WpT, d_out, nullptr, BT, CC, CC);
}